// Round 9
// baseline (307.959 us; speedup 1.0000x reference)
//
#include <hip/hip_runtime.h>
#include <hip/hip_fp16.h>

// GCN encoder: 3x (GCNConv + ReLU), dims 256->128->64->32
// N=50000 nodes, E=800000 edges. edge_index delivered as int32 (harness).
// R2: CSR gather instead of atomic scatter.
// R3: multi-block 3-phase scan.
// R4: packed 64-bit deg+cnt atomic, int2 CSR payload.
// R5: fp16 H gather buffer, dinv fused into scan.
// R6: MFMA fp16 GEMMs, fp16 activations.
// R7: rank from deg_hist atomic return -> atomic-free fill.
// R8: gemm column-split x2 (2x waves) + full K-unroll with A-prefetch
//     (was latency-bound: MfmaUtil 2.3%, VALUBusy 2.8%, occ 19%).

#define D0 256
#define D1 128
#define D2 64
#define D3 32

#define FIX_SCALE 16777216.0f           // 2^24 fixed-point for degree
#define FIX_INV   (1.0f / 16777216.0f)

typedef _Float16 half8 __attribute__((ext_vector_type(8)));
typedef float floatx4 __attribute__((ext_vector_type(4)));

// ------------------------------------------------- degree + histogram ------
__global__ void deg_hist_kernel(const int* __restrict__ ei, const float* __restrict__ ew,
                                unsigned long long* __restrict__ pk,
                                int* __restrict__ rank, int E) {
    int e = blockIdx.x * blockDim.x + threadIdx.x;
    if (e < E) {
        int c = ei[E + e];   // col (target)
        unsigned int wfix = (unsigned int)(ew[e] * FIX_SCALE + 0.5f);
        unsigned long long old = atomicAdd(&pk[c], (1ULL << 32) | (unsigned long long)wfix);
        rank[e] = (int)(old >> 32);
    }
}

// --------------------------------------------- 3-phase exclusive scan ------
__global__ __launch_bounds__(256) void scan_reduce(const unsigned long long* __restrict__ pk,
                                                   float* __restrict__ dinv,
                                                   int* __restrict__ cnt,
                                                   int* __restrict__ blockSum, int N) {
    __shared__ int s[256];
    const int t = threadIdx.x;
    const int i = blockIdx.x * 256 + t;
    int v = 0;
    if (i < N) {
        unsigned long long p = pk[i];
        float d = (float)(unsigned int)(p & 0xffffffffULL) * FIX_INV + 1.0f;  // +1 self-loop
        dinv[i] = rsqrtf(d);
        v = (int)(p >> 32);
        cnt[i] = v;
    }
    s[t] = v;
    __syncthreads();
#pragma unroll
    for (int off = 128; off > 0; off >>= 1) {
        if (t < off) s[t] += s[t + off];
        __syncthreads();
    }
    if (t == 0) blockSum[blockIdx.x] = s[0];
}

__global__ __launch_bounds__(256) void scan_blocksums(int* __restrict__ blockSum,
                                                      int* __restrict__ blockOff,
                                                      int* __restrict__ row_ptr_N,
                                                      int B) {
    __shared__ int s[256];
    const int t = threadIdx.x;
    const int v = (t < B) ? blockSum[t] : 0;
    s[t] = v;
    __syncthreads();
#pragma unroll
    for (int off = 1; off < 256; off <<= 1) {
        int u = (t >= off) ? s[t - off] : 0;
        __syncthreads();
        s[t] += u;
        __syncthreads();
    }
    if (t < B) blockOff[t] = s[t] - v;
    if (t == 255) *row_ptr_N = s[255];
}

__global__ __launch_bounds__(256) void scan_apply(const int* __restrict__ cnt,
                                                  const int* __restrict__ blockOff,
                                                  int* __restrict__ row_ptr, int N) {
    __shared__ int s[256];
    const int t = threadIdx.x;
    const int i = blockIdx.x * 256 + t;
    const int v = (i < N) ? cnt[i] : 0;
    s[t] = v;
    __syncthreads();
#pragma unroll
    for (int off = 1; off < 256; off <<= 1) {
        int u = (t >= off) ? s[t - off] : 0;
        __syncthreads();
        s[t] += u;
        __syncthreads();
    }
    if (i < N) row_ptr[i] = s[t] - v + blockOff[blockIdx.x];
}

// ------------------------------------------------- bucket fill (CSR) -------
__global__ void fill_kernel(const int* __restrict__ ei, const float* __restrict__ ew,
                            const float* __restrict__ dinv,
                            const int* __restrict__ row_ptr, const int* __restrict__ rank,
                            int2* __restrict__ pairs, int E) {
    int e = blockIdx.x * blockDim.x + threadIdx.x;
    if (e < E) {
        int r = ei[e];
        int c = ei[E + e];
        float w = dinv[r] * ew[e] * dinv[c];
        pairs[row_ptr[c] + rank[e]] = make_int2(r, __float_as_int(w));
    }
}

// ----------------------------------------------- W transpose+convert -------
template <int K, int DOUT>
__global__ void wcvt_kernel(const float* __restrict__ W, _Float16* __restrict__ Wt) {
    int idx = blockIdx.x * 256 + threadIdx.x;
    if (idx < K * DOUT) {
        int k = idx / DOUT, n = idx % DOUT;
        Wt[n * K + k] = (_Float16)W[idx];
    }
}

// ----------------------------------------------------------- MFMA GEMM -----
// H[N,BN] (fp16) = X[N,K] @ Wt^T, Wt is [BN][K] fp16.
// One wave owns a 16-row slab x CW output cols. Waves in a block share the
// slab (different col-groups). All A-frags prefetched into registers (full
// K-unroll), then B-load+MFMA stream (Wt is L2-hot).
// A[m=lane&15][k=quad*8+j]; B[k][n=lane&15]; D row=quad*4+reg.
template <int K, int BN, int CW, typename SRC>
__global__ __launch_bounds__(256) void mfma_gemm(const SRC* __restrict__ X,
                                                 const _Float16* __restrict__ Wt,
                                                 _Float16* __restrict__ H, int N) {
    constexpr int NT = CW / 16;       // col tiles per wave
    constexpr int CG = BN / CW;       // col groups (waves per slab)
    constexpr int NC = K / 32;        // k-chunks
    const int wid = blockIdx.x * 4 + (threadIdx.x >> 6);
    const int slab = wid / CG;
    const int cg = wid % CG;
    if (slab * 16 >= N) return;
    const int lane = threadIdx.x & 63;
    const int quad = lane >> 4;
    const int m = lane & 15;
    const int row = min(slab * 16 + m, N - 1);
    const int n0 = cg * CW;

    // ---- prefetch all A-frags ----
    half8 a[NC];
#pragma unroll
    for (int c = 0; c < NC; ++c) {
        if constexpr (sizeof(SRC) == 4) {
            const float* xp = (const float*)&X[(size_t)row * K + c * 32 + quad * 8];
            float4 f0 = *(const float4*)xp;
            float4 f1 = *(const float4*)(xp + 4);
            a[c][0] = (_Float16)f0.x; a[c][1] = (_Float16)f0.y;
            a[c][2] = (_Float16)f0.z; a[c][3] = (_Float16)f0.w;
            a[c][4] = (_Float16)f1.x; a[c][5] = (_Float16)f1.y;
            a[c][6] = (_Float16)f1.z; a[c][7] = (_Float16)f1.w;
        } else {
            a[c] = *(const half8*)&X[(size_t)row * K + c * 32 + quad * 8];
        }
    }

    floatx4 acc[NT];
#pragma unroll
    for (int t = 0; t < NT; ++t) acc[t] = (floatx4){0.f, 0.f, 0.f, 0.f};

#pragma unroll
    for (int c = 0; c < NC; ++c) {
#pragma unroll
        for (int t = 0; t < NT; ++t) {
            half8 b = *(const half8*)&Wt[(size_t)(n0 + t * 16 + m) * K + c * 32 + quad * 8];
            acc[t] = __builtin_amdgcn_mfma_f32_16x16x32_f16(a[c], b, acc[t], 0, 0, 0);
        }
    }

    const int r0 = slab * 16 + quad * 4;
#pragma unroll
    for (int t = 0; t < NT; ++t)
#pragma unroll
        for (int r = 0; r < 4; ++r)
            if (r0 + r < N)
                H[(size_t)(r0 + r) * BN + n0 + t * 16 + m] = (_Float16)acc[t][r];
}

// -------------------------------------------- fused aggregate + epilogue ----
template <int D, typename OUT>
__global__ __launch_bounds__(256) void agg_kernel(const _Float16* __restrict__ H,
                                                  const int* __restrict__ row_ptr,
                                                  const int2* __restrict__ pairs,
                                                  const float* __restrict__ dinv,
                                                  const float* __restrict__ bias,
                                                  OUT* __restrict__ out, int N) {
    constexpr int TPN = D / 8;        // threads per node (8 halves = 16B each)
    constexpr int NPB = 256 / TPN;    // nodes per block
    const int tid = threadIdx.x;
    const int g = tid / TPN;
    const int lane = tid % TPN;
    const int node = blockIdx.x * NPB + g;
    if (node >= N) return;

    const int beg = row_ptr[node];
    const int end = row_ptr[node + 1];
    float acc[8];
#pragma unroll
    for (int j = 0; j < 8; ++j) acc[j] = 0.0f;

    for (int k = beg; k < end; ++k) {
        int2 p = pairs[k];
        float w = __int_as_float(p.y);
        half8 u = *(const half8*)&H[(size_t)p.x * D + lane * 8];
#pragma unroll
        for (int j = 0; j < 8; ++j) acc[j] = fmaf(w, (float)u[j], acc[j]);
    }
    // self-loop + bias + relu
    float di = dinv[node];
    float d2 = di * di;
    {
        half8 u = *(const half8*)&H[(size_t)node * D + lane * 8];
#pragma unroll
        for (int j = 0; j < 8; ++j) acc[j] = fmaf(d2, (float)u[j], acc[j]);
    }
    float b[8];
    *(float4*)&b[0] = *(const float4*)&bias[lane * 8];
    *(float4*)&b[4] = *(const float4*)&bias[lane * 8 + 4];
#pragma unroll
    for (int j = 0; j < 8; ++j) acc[j] = fmaxf(acc[j] + b[j], 0.f);

    if constexpr (sizeof(OUT) == 2) {
        half8 o;
#pragma unroll
        for (int j = 0; j < 8; ++j) o[j] = (_Float16)acc[j];
        *(half8*)&out[(size_t)node * D + lane * 8] = o;
    } else {
        float* dst = (float*)&out[(size_t)node * D + lane * 8];
        *(float4*)&dst[0] = make_float4(acc[0], acc[1], acc[2], acc[3]);
        *(float4*)&dst[4] = make_float4(acc[4], acc[5], acc[6], acc[7]);
    }
}

// ---------------------------------------------------------------- launch ----
extern "C" void kernel_launch(void* const* d_in, const int* in_sizes, int n_in,
                              void* d_out, int out_size, void* d_ws, size_t ws_size,
                              hipStream_t stream) {
    const float* x   = (const float*)d_in[0];
    const int* ei    = (const int*)d_in[1];
    const float* ew  = (const float*)d_in[2];
    const float* W1  = (const float*)d_in[3];
    const float* b1  = (const float*)d_in[4];
    const float* W2  = (const float*)d_in[5];
    const float* b2  = (const float*)d_in[6];
    const float* W3  = (const float*)d_in[7];
    const float* b3  = (const float*)d_in[8];
    float* out = (float*)d_out;

    const int N = in_sizes[0] / D0;   // 50000
    const int E = in_sizes[2];        // 800000
    (void)n_in; (void)out_size; (void)ws_size;

    // ---- workspace carving ----
    char* ws = (char*)d_ws;
    size_t off = 0;
    auto carve = [&](size_t bytes) -> void* {
        void* p = (void*)(ws + off);
        off += (bytes + 255) & ~(size_t)255;
        return p;
    };
    unsigned long long* pk = (unsigned long long*)carve((size_t)N * 8);
    float* dinv    = (float*)carve((size_t)N * 4);
    int*   cnt     = (int*)carve((size_t)N * 4);
    int*   row_ptr = (int*)carve((size_t)(N + 1) * 4);
    int*   rank    = (int*)carve((size_t)E * 4);
    int*   bsum    = (int*)carve(256 * 4);
    int*   boff    = (int*)carve(256 * 4);
    int2*  pairs   = (int2*)carve((size_t)E * 8);
    _Float16* Wt1  = (_Float16*)carve((size_t)D0 * D1 * 2);
    _Float16* Wt2  = (_Float16*)carve((size_t)D1 * D2 * 2);
    _Float16* Wt3  = (_Float16*)carve((size_t)D2 * D3 * 2);
    _Float16* bufH = (_Float16*)carve((size_t)N * D1 * 2);  // h1/h2/h3
    _Float16* bufO = (_Float16*)carve((size_t)N * D1 * 2);  // out1/out2 (fp16)

    _Float16* h1   = bufH;               // N x 128 fp16
    _Float16* out1 = bufO;               // N x 128 fp16 ; x for layer 2
    _Float16* h2   = bufH;               // N x 64 fp16 (h1 dead)
    _Float16* out2 = bufO;               // N x 64 fp16 (out1 dead after gemm2)
    _Float16* h3   = bufH;               // N x 32 fp16 (h2 dead)

    const int eb = (E + 255) / 256;
    const int scanB = (N + 255) / 256;   // must be <= 256
    const int slabs = (N + 15) / 16;     // 3125

    // ---- weight transpose+convert (independent of CSR build) ----
    wcvt_kernel<D0, D1><<<(D0 * D1 + 255) / 256, 256, 0, stream>>>(W1, Wt1);
    wcvt_kernel<D1, D2><<<(D1 * D2 + 255) / 256, 256, 0, stream>>>(W2, Wt2);
    wcvt_kernel<D2, D3><<<(D2 * D3 + 255) / 256, 256, 0, stream>>>(W3, Wt3);

    // ---- CSR build + normalization ----
    hipMemsetAsync(pk, 0, (size_t)N * 8, stream);
    deg_hist_kernel<<<eb, 256, 0, stream>>>(ei, ew, pk, rank, E);
    scan_reduce<<<scanB, 256, 0, stream>>>(pk, dinv, cnt, bsum, N);
    scan_blocksums<<<1, 256, 0, stream>>>(bsum, boff, &row_ptr[N], scanB);
    scan_apply<<<scanB, 256, 0, stream>>>(cnt, boff, row_ptr, N);
    fill_kernel<<<eb, 256, 0, stream>>>(ei, ew, dinv, row_ptr, rank, pairs, E);

    // ---- layer 1: 256 -> 128  (CW=64 -> 2 col-groups, 6250 waves) ----
    {
        const int wavesT = slabs * 2;
        mfma_gemm<D0, D1, 64, float><<<(wavesT + 3) / 4, 256, 0, stream>>>(x, Wt1, h1, N);
    }
    agg_kernel<D1, _Float16><<<(N + 15) / 16, 256, 0, stream>>>(h1, row_ptr, pairs, dinv, b1, out1, N);

    // ---- layer 2: 128 -> 64  (CW=32 -> 2 col-groups, 6250 waves) ----
    {
        const int wavesT = slabs * 2;
        mfma_gemm<D1, D2, 32, _Float16><<<(wavesT + 3) / 4, 256, 0, stream>>>(out1, Wt2, h2, N);
    }
    agg_kernel<D2, _Float16><<<(N + 31) / 32, 256, 0, stream>>>(h2, row_ptr, pairs, dinv, b2, out2, N);

    // ---- layer 3: 64 -> 32  (CW=32, 3125 waves) ----
    mfma_gemm<D2, D3, 32, _Float16><<<(slabs + 3) / 4, 256, 0, stream>>>(out2, Wt3, h3, N);
    agg_kernel<D3, float><<<(N + 63) / 64, 256, 0, stream>>>(h3, row_ptr, pairs, dinv, b3, out, N);
}

// Round 10
// 307.179 us; speedup vs baseline: 1.0025x; 1.0025x over previous
//
#include <hip/hip_runtime.h>
#include <hip/hip_fp16.h>

// GCN encoder: 3x (GCNConv + ReLU), dims 256->128->64->32
// N=50000 nodes, E=800000 edges. edge_index delivered as int32 (harness).
// R2: CSR gather.  R3: multi-block scan.  R4: packed deg+cnt atomic.
// R5: fp16 H buffers.  R6: MFMA gemms.  R7: atomic-free fill via rank.
// R8: col-split (failed: VGPR=48 -> serial B-load->MFMA chain).
// R9: block-cooperative gemm: A staged in LDS in fragment order (conflict-
//     free ds_read_b128), B manually double-buffered in registers.

#define D0 256
#define D1 128
#define D2 64
#define D3 32

#define FIX_SCALE 16777216.0f           // 2^24 fixed-point for degree
#define FIX_INV   (1.0f / 16777216.0f)

typedef _Float16 half8 __attribute__((ext_vector_type(8)));
typedef float floatx4 __attribute__((ext_vector_type(4)));

// ------------------------------------------------- degree + histogram ------
__global__ void deg_hist_kernel(const int* __restrict__ ei, const float* __restrict__ ew,
                                unsigned long long* __restrict__ pk,
                                int* __restrict__ rank, int E) {
    int e = blockIdx.x * blockDim.x + threadIdx.x;
    if (e < E) {
        int c = ei[E + e];   // col (target)
        unsigned int wfix = (unsigned int)(ew[e] * FIX_SCALE + 0.5f);
        unsigned long long old = atomicAdd(&pk[c], (1ULL << 32) | (unsigned long long)wfix);
        rank[e] = (int)(old >> 32);
    }
}

// --------------------------------------------- 3-phase exclusive scan ------
__global__ __launch_bounds__(256) void scan_reduce(const unsigned long long* __restrict__ pk,
                                                   float* __restrict__ dinv,
                                                   int* __restrict__ cnt,
                                                   int* __restrict__ blockSum, int N) {
    __shared__ int s[256];
    const int t = threadIdx.x;
    const int i = blockIdx.x * 256 + t;
    int v = 0;
    if (i < N) {
        unsigned long long p = pk[i];
        float d = (float)(unsigned int)(p & 0xffffffffULL) * FIX_INV + 1.0f;  // +1 self-loop
        dinv[i] = rsqrtf(d);
        v = (int)(p >> 32);
        cnt[i] = v;
    }
    s[t] = v;
    __syncthreads();
#pragma unroll
    for (int off = 128; off > 0; off >>= 1) {
        if (t < off) s[t] += s[t + off];
        __syncthreads();
    }
    if (t == 0) blockSum[blockIdx.x] = s[0];
}

__global__ __launch_bounds__(256) void scan_blocksums(int* __restrict__ blockSum,
                                                      int* __restrict__ blockOff,
                                                      int* __restrict__ row_ptr_N,
                                                      int B) {
    __shared__ int s[256];
    const int t = threadIdx.x;
    const int v = (t < B) ? blockSum[t] : 0;
    s[t] = v;
    __syncthreads();
#pragma unroll
    for (int off = 1; off < 256; off <<= 1) {
        int u = (t >= off) ? s[t - off] : 0;
        __syncthreads();
        s[t] += u;
        __syncthreads();
    }
    if (t < B) blockOff[t] = s[t] - v;
    if (t == 255) *row_ptr_N = s[255];
}

__global__ __launch_bounds__(256) void scan_apply(const int* __restrict__ cnt,
                                                  const int* __restrict__ blockOff,
                                                  int* __restrict__ row_ptr, int N) {
    __shared__ int s[256];
    const int t = threadIdx.x;
    const int i = blockIdx.x * 256 + t;
    const int v = (i < N) ? cnt[i] : 0;
    s[t] = v;
    __syncthreads();
#pragma unroll
    for (int off = 1; off < 256; off <<= 1) {
        int u = (t >= off) ? s[t - off] : 0;
        __syncthreads();
        s[t] += u;
        __syncthreads();
    }
    if (i < N) row_ptr[i] = s[t] - v + blockOff[blockIdx.x];
}

// ------------------------------------------------- bucket fill (CSR) -------
__global__ void fill_kernel(const int* __restrict__ ei, const float* __restrict__ ew,
                            const float* __restrict__ dinv,
                            const int* __restrict__ row_ptr, const int* __restrict__ rank,
                            int2* __restrict__ pairs, int E) {
    int e = blockIdx.x * blockDim.x + threadIdx.x;
    if (e < E) {
        int r = ei[e];
        int c = ei[E + e];
        float w = dinv[r] * ew[e] * dinv[c];
        pairs[row_ptr[c] + rank[e]] = make_int2(r, __float_as_int(w));
    }
}

// ----------------------------------------------- W transpose+convert -------
template <int K, int DOUT>
__global__ void wcvt_kernel(const float* __restrict__ W, _Float16* __restrict__ Wt) {
    int idx = blockIdx.x * 256 + threadIdx.x;
    if (idx < K * DOUT) {
        int k = idx / DOUT, n = idx % DOUT;
        Wt[n * K + k] = (_Float16)W[idx];
    }
}

// ----------------------------------------------------------- MFMA GEMM -----
// H[N,BN] (fp16) = X[N,K] @ Wt^T, Wt is [BN][K] fp16.
// Block = 256 threads = 4 waves = 64 rows (4 slabs of 16). A tile staged in
// LDS in MFMA fragment order; each wave computes its slab x all BN cols.
// B-frags manually double-buffered in registers (tile t+1 prefetched during
// tile t's MFMAs).  A[m][k=quad*8+j]; B[k][n=lane&15]; D row=quad*4+reg.
template <int K, int BN, typename SRC>
__global__ __launch_bounds__(256) void mfma_gemm(const SRC* __restrict__ X,
                                                 const _Float16* __restrict__ Wt,
                                                 _Float16* __restrict__ H, int N) {
    constexpr int NC = K / 32;        // k-chunks
    constexpr int NT = BN / 16;       // col tiles per wave
    __shared__ _Float16 Alds[4 * NC * 4 * 16 * 8];   // frag-ordered, NC*4KB

    const int tid = threadIdx.x;
    const int row0 = blockIdx.x * 64;

    // ---- stage A (64 rows x K) into LDS, fragment order ----
    {
        const int rl = tid >> 2;          // 0..63
        const int s = rl >> 4, mm = rl & 15;
        const int cg = tid & 3;           // quarter-row column group
        const int r = row0 + rl;
        const SRC* xrow = &X[(size_t)min(r, N - 1) * K + cg * (K / 4)];
#pragma unroll
        for (int i = 0; i < K / 32; ++i) {
            half8 v;
            if constexpr (sizeof(SRC) == 4) {
                float4 f0 = *(const float4*)&xrow[i * 8];
                float4 f1 = *(const float4*)&xrow[i * 8 + 4];
                v[0] = (_Float16)f0.x; v[1] = (_Float16)f0.y;
                v[2] = (_Float16)f0.z; v[3] = (_Float16)f0.w;
                v[4] = (_Float16)f1.x; v[5] = (_Float16)f1.y;
                v[6] = (_Float16)f1.z; v[7] = (_Float16)f1.w;
            } else {
                v = *(const half8*)&xrow[i * 8];
            }
            int col = cg * (K / 4) + i * 8;
            int c = col >> 5;
            int q = (col & 31) >> 3;
            *(half8*)&Alds[(((s * NC + c) * 4 + q) * 16 + mm) * 8] = v;
        }
    }
    __syncthreads();

    // ---- compute: wave w = slab w ----
    const int wave = tid >> 6;
    const int lane = tid & 63;
    const int quad = lane >> 4;
    const int m = lane & 15;

    half8 a[NC];
#pragma unroll
    for (int c = 0; c < NC; ++c)
        a[c] = *(const half8*)&Alds[(((wave * NC + c) * 4 + quad) * 16 + m) * 8];

    floatx4 acc[NT];
#pragma unroll
    for (int t = 0; t < NT; ++t) acc[t] = (floatx4){0.f, 0.f, 0.f, 0.f};

    half8 b0[NC], b1[NC];
#pragma unroll
    for (int c = 0; c < NC; ++c)
        b0[c] = *(const half8*)&Wt[(size_t)m * K + c * 32 + quad * 8];

#pragma unroll
    for (int t = 0; t < NT; ++t) {
        if (t + 1 < NT) {
            if (t & 1) {
#pragma unroll
                for (int c = 0; c < NC; ++c)
                    b0[c] = *(const half8*)&Wt[(size_t)((t + 1) * 16 + m) * K + c * 32 + quad * 8];
            } else {
#pragma unroll
                for (int c = 0; c < NC; ++c)
                    b1[c] = *(const half8*)&Wt[(size_t)((t + 1) * 16 + m) * K + c * 32 + quad * 8];
            }
        }
#pragma unroll
        for (int c = 0; c < NC; ++c) {
            half8 b = (t & 1) ? b1[c] : b0[c];
            acc[t] = __builtin_amdgcn_mfma_f32_16x16x32_f16(a[c], b, acc[t], 0, 0, 0);
        }
    }

    const int r0 = row0 + wave * 16 + quad * 4;
#pragma unroll
    for (int t = 0; t < NT; ++t)
#pragma unroll
        for (int r = 0; r < 4; ++r)
            if (r0 + r < N)
                H[(size_t)(r0 + r) * BN + t * 16 + m] = (_Float16)acc[t][r];
}

// -------------------------------------------- fused aggregate + epilogue ----
template <int D, typename OUT>
__global__ __launch_bounds__(256) void agg_kernel(const _Float16* __restrict__ H,
                                                  const int* __restrict__ row_ptr,
                                                  const int2* __restrict__ pairs,
                                                  const float* __restrict__ dinv,
                                                  const float* __restrict__ bias,
                                                  OUT* __restrict__ out, int N) {
    constexpr int TPN = D / 8;        // threads per node (8 halves = 16B each)
    constexpr int NPB = 256 / TPN;    // nodes per block
    const int tid = threadIdx.x;
    const int g = tid / TPN;
    const int lane = tid % TPN;
    const int node = blockIdx.x * NPB + g;
    if (node >= N) return;

    const int beg = row_ptr[node];
    const int end = row_ptr[node + 1];
    float acc[8];
#pragma unroll
    for (int j = 0; j < 8; ++j) acc[j] = 0.0f;

    for (int k = beg; k < end; ++k) {
        int2 p = pairs[k];
        float w = __int_as_float(p.y);
        half8 u = *(const half8*)&H[(size_t)p.x * D + lane * 8];
#pragma unroll
        for (int j = 0; j < 8; ++j) acc[j] = fmaf(w, (float)u[j], acc[j]);
    }
    // self-loop + bias + relu
    float di = dinv[node];
    float d2 = di * di;
    {
        half8 u = *(const half8*)&H[(size_t)node * D + lane * 8];
#pragma unroll
        for (int j = 0; j < 8; ++j) acc[j] = fmaf(d2, (float)u[j], acc[j]);
    }
    float b[8];
    *(float4*)&b[0] = *(const float4*)&bias[lane * 8];
    *(float4*)&b[4] = *(const float4*)&bias[lane * 8 + 4];
#pragma unroll
    for (int j = 0; j < 8; ++j) acc[j] = fmaxf(acc[j] + b[j], 0.f);

    if constexpr (sizeof(OUT) == 2) {
        half8 o;
#pragma unroll
        for (int j = 0; j < 8; ++j) o[j] = (_Float16)acc[j];
        *(half8*)&out[(size_t)node * D + lane * 8] = o;
    } else {
        float* dst = (float*)&out[(size_t)node * D + lane * 8];
        *(float4*)&dst[0] = make_float4(acc[0], acc[1], acc[2], acc[3]);
        *(float4*)&dst[4] = make_float4(acc[4], acc[5], acc[6], acc[7]);
    }
}

// ---------------------------------------------------------------- launch ----
extern "C" void kernel_launch(void* const* d_in, const int* in_sizes, int n_in,
                              void* d_out, int out_size, void* d_ws, size_t ws_size,
                              hipStream_t stream) {
    const float* x   = (const float*)d_in[0];
    const int* ei    = (const int*)d_in[1];
    const float* ew  = (const float*)d_in[2];
    const float* W1  = (const float*)d_in[3];
    const float* b1  = (const float*)d_in[4];
    const float* W2  = (const float*)d_in[5];
    const float* b2  = (const float*)d_in[6];
    const float* W3  = (const float*)d_in[7];
    const float* b3  = (const float*)d_in[8];
    float* out = (float*)d_out;

    const int N = in_sizes[0] / D0;   // 50000
    const int E = in_sizes[2];        // 800000
    (void)n_in; (void)out_size; (void)ws_size;

    // ---- workspace carving ----
    char* ws = (char*)d_ws;
    size_t off = 0;
    auto carve = [&](size_t bytes) -> void* {
        void* p = (void*)(ws + off);
        off += (bytes + 255) & ~(size_t)255;
        return p;
    };
    unsigned long long* pk = (unsigned long long*)carve((size_t)N * 8);
    float* dinv    = (float*)carve((size_t)N * 4);
    int*   cnt     = (int*)carve((size_t)N * 4);
    int*   row_ptr = (int*)carve((size_t)(N + 1) * 4);
    int*   rank    = (int*)carve((size_t)E * 4);
    int*   bsum    = (int*)carve(256 * 4);
    int*   boff    = (int*)carve(256 * 4);
    int2*  pairs   = (int2*)carve((size_t)E * 8);
    _Float16* Wt1  = (_Float16*)carve((size_t)D0 * D1 * 2);
    _Float16* Wt2  = (_Float16*)carve((size_t)D1 * D2 * 2);
    _Float16* Wt3  = (_Float16*)carve((size_t)D2 * D3 * 2);
    _Float16* bufH = (_Float16*)carve((size_t)N * D1 * 2);  // h1/h2/h3
    _Float16* bufO = (_Float16*)carve((size_t)N * D1 * 2);  // out1/out2 (fp16)

    _Float16* h1   = bufH;               // N x 128 fp16
    _Float16* out1 = bufO;               // N x 128 fp16 ; x for layer 2
    _Float16* h2   = bufH;               // N x 64 fp16 (h1 dead)
    _Float16* out2 = bufO;               // N x 64 fp16 (out1 dead after gemm2)
    _Float16* h3   = bufH;               // N x 32 fp16 (h2 dead)

    const int eb = (E + 255) / 256;
    const int scanB = (N + 255) / 256;   // must be <= 256
    const int gB = (N + 63) / 64;        // 782 gemm blocks

    // ---- weight transpose+convert (independent of CSR build) ----
    wcvt_kernel<D0, D1><<<(D0 * D1 + 255) / 256, 256, 0, stream>>>(W1, Wt1);
    wcvt_kernel<D1, D2><<<(D1 * D2 + 255) / 256, 256, 0, stream>>>(W2, Wt2);
    wcvt_kernel<D2, D3><<<(D2 * D3 + 255) / 256, 256, 0, stream>>>(W3, Wt3);

    // ---- CSR build + normalization ----
    hipMemsetAsync(pk, 0, (size_t)N * 8, stream);
    deg_hist_kernel<<<eb, 256, 0, stream>>>(ei, ew, pk, rank, E);
    scan_reduce<<<scanB, 256, 0, stream>>>(pk, dinv, cnt, bsum, N);
    scan_blocksums<<<1, 256, 0, stream>>>(bsum, boff, &row_ptr[N], scanB);
    scan_apply<<<scanB, 256, 0, stream>>>(cnt, boff, row_ptr, N);
    fill_kernel<<<eb, 256, 0, stream>>>(ei, ew, dinv, row_ptr, rank, pairs, E);

    // ---- layer 1: 256 -> 128 ----
    mfma_gemm<D0, D1, float><<<gB, 256, 0, stream>>>(x, Wt1, h1, N);
    agg_kernel<D1, _Float16><<<(N + 15) / 16, 256, 0, stream>>>(h1, row_ptr, pairs, dinv, b1, out1, N);

    // ---- layer 2: 128 -> 64 ----
    mfma_gemm<D1, D2, _Float16><<<gB, 256, 0, stream>>>(out1, Wt2, h2, N);
    agg_kernel<D2, _Float16><<<(N + 31) / 32, 256, 0, stream>>>(h2, row_ptr, pairs, dinv, b2, out2, N);

    // ---- layer 3: 64 -> 32 ----
    mfma_gemm<D2, D3, _Float16><<<gB, 256, 0, stream>>>(out2, Wt3, h3, N);
    agg_kernel<D3, float><<<(N + 63) / 64, 256, 0, stream>>>(h3, row_ptr, pairs, dinv, b3, out, N);
}

// Round 11
// 296.646 us; speedup vs baseline: 1.0381x; 1.0355x over previous
//
#include <hip/hip_runtime.h>
#include <hip/hip_fp16.h>

// GCN encoder: 3x (GCNConv + ReLU), dims 256->128->64->32
// N=50000 nodes, E=800000 edges. edge_index delivered as int32 (harness).
// R2: CSR gather.  R3: multi-block scan.  R4: packed deg+cnt atomic.
// R5: fp16 H buffers.  R6: MFMA gemms.  R7: atomic-free fill via rank.
// R8/R9: failed gemm pipelining (compiler sinks B-loads; VGPR stayed ~50).
// R10: persistent-B gemm: each wave holds its 32-col B-frags in registers
//      (loop-invariant -> can't be sunk), grid-strides over row slabs with
//      A prefetch. x pre-converted to fp16 (xcvt) so all gemms share fp16 A.

#define D0 256
#define D1 128
#define D2 64
#define D3 32

#define FIX_SCALE 16777216.0f           // 2^24 fixed-point for degree
#define FIX_INV   (1.0f / 16777216.0f)

typedef _Float16 half8 __attribute__((ext_vector_type(8)));
typedef float floatx4 __attribute__((ext_vector_type(4)));

// ------------------------------------------------- degree + histogram ------
__global__ void deg_hist_kernel(const int* __restrict__ ei, const float* __restrict__ ew,
                                unsigned long long* __restrict__ pk,
                                int* __restrict__ rank, int E) {
    int e = blockIdx.x * blockDim.x + threadIdx.x;
    if (e < E) {
        int c = ei[E + e];   // col (target)
        unsigned int wfix = (unsigned int)(ew[e] * FIX_SCALE + 0.5f);
        unsigned long long old = atomicAdd(&pk[c], (1ULL << 32) | (unsigned long long)wfix);
        rank[e] = (int)(old >> 32);
    }
}

// --------------------------------------------- 3-phase exclusive scan ------
__global__ __launch_bounds__(256) void scan_reduce(const unsigned long long* __restrict__ pk,
                                                   float* __restrict__ dinv,
                                                   int* __restrict__ cnt,
                                                   int* __restrict__ blockSum, int N) {
    __shared__ int s[256];
    const int t = threadIdx.x;
    const int i = blockIdx.x * 256 + t;
    int v = 0;
    if (i < N) {
        unsigned long long p = pk[i];
        float d = (float)(unsigned int)(p & 0xffffffffULL) * FIX_INV + 1.0f;  // +1 self-loop
        dinv[i] = rsqrtf(d);
        v = (int)(p >> 32);
        cnt[i] = v;
    }
    s[t] = v;
    __syncthreads();
#pragma unroll
    for (int off = 128; off > 0; off >>= 1) {
        if (t < off) s[t] += s[t + off];
        __syncthreads();
    }
    if (t == 0) blockSum[blockIdx.x] = s[0];
}

__global__ __launch_bounds__(256) void scan_blocksums(int* __restrict__ blockSum,
                                                      int* __restrict__ blockOff,
                                                      int* __restrict__ row_ptr_N,
                                                      int B) {
    __shared__ int s[256];
    const int t = threadIdx.x;
    const int v = (t < B) ? blockSum[t] : 0;
    s[t] = v;
    __syncthreads();
#pragma unroll
    for (int off = 1; off < 256; off <<= 1) {
        int u = (t >= off) ? s[t - off] : 0;
        __syncthreads();
        s[t] += u;
        __syncthreads();
    }
    if (t < B) blockOff[t] = s[t] - v;
    if (t == 255) *row_ptr_N = s[255];
}

__global__ __launch_bounds__(256) void scan_apply(const int* __restrict__ cnt,
                                                  const int* __restrict__ blockOff,
                                                  int* __restrict__ row_ptr, int N) {
    __shared__ int s[256];
    const int t = threadIdx.x;
    const int i = blockIdx.x * 256 + t;
    const int v = (i < N) ? cnt[i] : 0;
    s[t] = v;
    __syncthreads();
#pragma unroll
    for (int off = 1; off < 256; off <<= 1) {
        int u = (t >= off) ? s[t - off] : 0;
        __syncthreads();
        s[t] += u;
        __syncthreads();
    }
    if (i < N) row_ptr[i] = s[t] - v + blockOff[blockIdx.x];
}

// ------------------------------------------------- bucket fill (CSR) -------
__global__ void fill_kernel(const int* __restrict__ ei, const float* __restrict__ ew,
                            const float* __restrict__ dinv,
                            const int* __restrict__ row_ptr, const int* __restrict__ rank,
                            int2* __restrict__ pairs, int E) {
    int e = blockIdx.x * blockDim.x + threadIdx.x;
    if (e < E) {
        int r = ei[e];
        int c = ei[E + e];
        float w = dinv[r] * ew[e] * dinv[c];
        pairs[row_ptr[c] + rank[e]] = make_int2(r, __float_as_int(w));
    }
}

// ----------------------------------------------- W transpose+convert -------
template <int K, int DOUT>
__global__ void wcvt_kernel(const float* __restrict__ W, _Float16* __restrict__ Wt) {
    int idx = blockIdx.x * 256 + threadIdx.x;
    if (idx < K * DOUT) {
        int k = idx / DOUT, n = idx % DOUT;
        Wt[n * K + k] = (_Float16)W[idx];
    }
}

// ----------------------------------------------- x fp32 -> fp16 convert ----
__global__ __launch_bounds__(256) void xcvt_kernel(const float* __restrict__ x,
                                                   _Float16* __restrict__ x16, int total) {
    int i = (blockIdx.x * 256 + threadIdx.x) * 8;
    if (i < total) {
        float4 f0 = *(const float4*)&x[i];
        float4 f1 = *(const float4*)&x[i + 4];
        half8 v;
        v[0] = (_Float16)f0.x; v[1] = (_Float16)f0.y;
        v[2] = (_Float16)f0.z; v[3] = (_Float16)f0.w;
        v[4] = (_Float16)f1.x; v[5] = (_Float16)f1.y;
        v[6] = (_Float16)f1.z; v[7] = (_Float16)f1.w;
        *(half8*)&x16[i] = v;
    }
}

// ----------------------------------------------------------- MFMA GEMM -----
// H[N,BN] (fp16) = X[N,K] (fp16) @ Wt^T, Wt is [BN][K] fp16.
// Each wave owns a fixed 32-col group (2 MFMA tiles): B-frags loaded ONCE
// into registers (loop-invariant), then grid-stride over 16-row slabs with
// next-slab A prefetch. Two interleaved acc chains; no LDS, no barriers.
// A[m=lane&15][k=quad*8+j]; B[k][n=lane&15]; D row=quad*4+reg.
template <int K, int BN>
__global__ __launch_bounds__(256) void mfma_gemm(const _Float16* __restrict__ X,
                                                 const _Float16* __restrict__ Wt,
                                                 _Float16* __restrict__ H, int N) {
    constexpr int NC = K / 32;        // k-chunks
    constexpr int CG = BN / 32;       // col groups (waves per slab)
    const int w = blockIdx.x * 4 + (threadIdx.x >> 6);
    const int lane = threadIdx.x & 63;
    const int quad = lane >> 4;
    const int m = lane & 15;
    const int cg = w & (CG - 1);
    const int nslab = N >> 4;         // N multiple of 16 (50000 = 3125*16)
    const int stride = (gridDim.x * 4) / CG;
    int slab = w / CG;
    if (slab >= nslab) return;
    const int n0 = cg * 32;

    // ---- persistent B-frags (2 tiles x NC chunks), loop-invariant ----
    half8 b0[NC], b1[NC];
#pragma unroll
    for (int c = 0; c < NC; ++c) {
        b0[c] = *(const half8*)&Wt[(size_t)(n0 + m) * K + c * 32 + quad * 8];
        b1[c] = *(const half8*)&Wt[(size_t)(n0 + 16 + m) * K + c * 32 + quad * 8];
    }

    // ---- prefetch A for first slab ----
    half8 a[NC];
#pragma unroll
    for (int c = 0; c < NC; ++c)
        a[c] = *(const half8*)&X[(size_t)(slab * 16 + m) * K + c * 32 + quad * 8];

    while (true) {
        const int next = slab + stride;
        half8 an[NC];
        if (next < nslab) {
#pragma unroll
            for (int c = 0; c < NC; ++c)
                an[c] = *(const half8*)&X[(size_t)(next * 16 + m) * K + c * 32 + quad * 8];
        }

        floatx4 acc0 = (floatx4){0.f, 0.f, 0.f, 0.f};
        floatx4 acc1 = (floatx4){0.f, 0.f, 0.f, 0.f};
#pragma unroll
        for (int c = 0; c < NC; ++c) {
            acc0 = __builtin_amdgcn_mfma_f32_16x16x32_f16(a[c], b0[c], acc0, 0, 0, 0);
            acc1 = __builtin_amdgcn_mfma_f32_16x16x32_f16(a[c], b1[c], acc1, 0, 0, 0);
        }

        const int r0 = slab * 16 + quad * 4;
#pragma unroll
        for (int r = 0; r < 4; ++r) {
            H[(size_t)(r0 + r) * BN + n0 + m]      = (_Float16)acc0[r];
            H[(size_t)(r0 + r) * BN + n0 + 16 + m] = (_Float16)acc1[r];
        }

        if (next >= nslab) break;
        slab = next;
#pragma unroll
        for (int c = 0; c < NC; ++c) a[c] = an[c];
    }
}

// -------------------------------------------- fused aggregate + epilogue ----
template <int D, typename OUT>
__global__ __launch_bounds__(256) void agg_kernel(const _Float16* __restrict__ H,
                                                  const int* __restrict__ row_ptr,
                                                  const int2* __restrict__ pairs,
                                                  const float* __restrict__ dinv,
                                                  const float* __restrict__ bias,
                                                  OUT* __restrict__ out, int N) {
    constexpr int TPN = D / 8;        // threads per node (8 halves = 16B each)
    constexpr int NPB = 256 / TPN;    // nodes per block
    const int tid = threadIdx.x;
    const int g = tid / TPN;
    const int lane = tid % TPN;
    const int node = blockIdx.x * NPB + g;
    if (node >= N) return;

    const int beg = row_ptr[node];
    const int end = row_ptr[node + 1];
    float acc[8];
#pragma unroll
    for (int j = 0; j < 8; ++j) acc[j] = 0.0f;

    for (int k = beg; k < end; ++k) {
        int2 p = pairs[k];
        float w = __int_as_float(p.y);
        half8 u = *(const half8*)&H[(size_t)p.x * D + lane * 8];
#pragma unroll
        for (int j = 0; j < 8; ++j) acc[j] = fmaf(w, (float)u[j], acc[j]);
    }
    // self-loop + bias + relu
    float di = dinv[node];
    float d2 = di * di;
    {
        half8 u = *(const half8*)&H[(size_t)node * D + lane * 8];
#pragma unroll
        for (int j = 0; j < 8; ++j) acc[j] = fmaf(d2, (float)u[j], acc[j]);
    }
    float b[8];
    *(float4*)&b[0] = *(const float4*)&bias[lane * 8];
    *(float4*)&b[4] = *(const float4*)&bias[lane * 8 + 4];
#pragma unroll
    for (int j = 0; j < 8; ++j) acc[j] = fmaxf(acc[j] + b[j], 0.f);

    if constexpr (sizeof(OUT) == 2) {
        half8 o;
#pragma unroll
        for (int j = 0; j < 8; ++j) o[j] = (_Float16)acc[j];
        *(half8*)&out[(size_t)node * D + lane * 8] = o;
    } else {
        float* dst = (float*)&out[(size_t)node * D + lane * 8];
        *(float4*)&dst[0] = make_float4(acc[0], acc[1], acc[2], acc[3]);
        *(float4*)&dst[4] = make_float4(acc[4], acc[5], acc[6], acc[7]);
    }
}

// ---------------------------------------------------------------- launch ----
extern "C" void kernel_launch(void* const* d_in, const int* in_sizes, int n_in,
                              void* d_out, int out_size, void* d_ws, size_t ws_size,
                              hipStream_t stream) {
    const float* x   = (const float*)d_in[0];
    const int* ei    = (const int*)d_in[1];
    const float* ew  = (const float*)d_in[2];
    const float* W1  = (const float*)d_in[3];
    const float* b1  = (const float*)d_in[4];
    const float* W2  = (const float*)d_in[5];
    const float* b2  = (const float*)d_in[6];
    const float* W3  = (const float*)d_in[7];
    const float* b3  = (const float*)d_in[8];
    float* out = (float*)d_out;

    const int N = in_sizes[0] / D0;   // 50000
    const int E = in_sizes[2];        // 800000
    (void)n_in; (void)out_size; (void)ws_size;

    // ---- workspace carving ----
    char* ws = (char*)d_ws;
    size_t off = 0;
    auto carve = [&](size_t bytes) -> void* {
        void* p = (void*)(ws + off);
        off += (bytes + 255) & ~(size_t)255;
        return p;
    };
    unsigned long long* pk = (unsigned long long*)carve((size_t)N * 8);
    float* dinv    = (float*)carve((size_t)N * 4);
    int*   cnt     = (int*)carve((size_t)N * 4);
    int*   row_ptr = (int*)carve((size_t)(N + 1) * 4);
    int*   rank    = (int*)carve((size_t)E * 4);
    int*   bsum    = (int*)carve(256 * 4);
    int*   boff    = (int*)carve(256 * 4);
    int2*  pairs   = (int2*)carve((size_t)E * 8);
    _Float16* Wt1  = (_Float16*)carve((size_t)D0 * D1 * 2);
    _Float16* Wt2  = (_Float16*)carve((size_t)D1 * D2 * 2);
    _Float16* Wt3  = (_Float16*)carve((size_t)D2 * D3 * 2);
    _Float16* x16  = (_Float16*)carve((size_t)N * D0 * 2);  // 25.6 MB
    _Float16* bufH = (_Float16*)carve((size_t)N * D1 * 2);  // h1/h2/h3
    _Float16* bufO = (_Float16*)carve((size_t)N * D1 * 2);  // out1/out2 (fp16)

    _Float16* h1   = bufH;               // N x 128 fp16
    _Float16* out1 = bufO;               // N x 128 fp16 ; x for layer 2
    _Float16* h2   = bufH;               // N x 64 fp16 (h1 dead)
    _Float16* out2 = bufO;               // N x 64 fp16 (out1 dead after gemm2)
    _Float16* h3   = bufH;               // N x 32 fp16 (h2 dead)

    const int eb = (E + 255) / 256;
    const int scanB = (N + 255) / 256;   // must be <= 256
    const int gB = 768;                  // gemm blocks (3/CU, 3072 waves)

    // ---- x convert + weight transpose (independent of CSR build) ----
    xcvt_kernel<<<(N * D0 / 8 + 255) / 256, 256, 0, stream>>>(x, x16, N * D0);
    wcvt_kernel<D0, D1><<<(D0 * D1 + 255) / 256, 256, 0, stream>>>(W1, Wt1);
    wcvt_kernel<D1, D2><<<(D1 * D2 + 255) / 256, 256, 0, stream>>>(W2, Wt2);
    wcvt_kernel<D2, D3><<<(D2 * D3 + 255) / 256, 256, 0, stream>>>(W3, Wt3);

    // ---- CSR build + normalization ----
    hipMemsetAsync(pk, 0, (size_t)N * 8, stream);
    deg_hist_kernel<<<eb, 256, 0, stream>>>(ei, ew, pk, rank, E);
    scan_reduce<<<scanB, 256, 0, stream>>>(pk, dinv, cnt, bsum, N);
    scan_blocksums<<<1, 256, 0, stream>>>(bsum, boff, &row_ptr[N], scanB);
    scan_apply<<<scanB, 256, 0, stream>>>(cnt, boff, row_ptr, N);
    fill_kernel<<<eb, 256, 0, stream>>>(ei, ew, dinv, row_ptr, rank, pairs, E);

    // ---- layer 1: 256 -> 128 ----
    mfma_gemm<D0, D1><<<gB, 256, 0, stream>>>(x16, Wt1, h1, N);
    agg_kernel<D1, _Float16><<<(N + 15) / 16, 256, 0, stream>>>(h1, row_ptr, pairs, dinv, b1, out1, N);

    // ---- layer 2: 128 -> 64 ----
    mfma_gemm<D1, D2><<<gB, 256, 0, stream>>>(out1, Wt2, h2, N);
    agg_kernel<D2, _Float16><<<(N + 31) / 32, 256, 0, stream>>>(h2, row_ptr, pairs, dinv, b2, out2, N);

    // ---- layer 3: 64 -> 32 ----
    mfma_gemm<D2, D3><<<gB, 256, 0, stream>>>(out2, Wt3, h3, N);
    agg_kernel<D3, float><<<(N + 63) / 64, 256, 0, stream>>>(h3, row_ptr, pairs, dinv, b3, out, N);
}

// Round 12
// 268.995 us; speedup vs baseline: 1.1449x; 1.1028x over previous
//
#include <hip/hip_runtime.h>
#include <hip/hip_fp16.h>

// GCN encoder: 3x (GCNConv + ReLU), dims 256->128->64->32
// N=50000 nodes, E=800000 edges. edge_index delivered as int32 (harness).
// R2: CSR gather.  R3: multi-block scan.  R4: packed deg+cnt atomic.
// R5: fp16 H buffers.  R6: MFMA gemms.  R7: atomic-free fill via rank.
// R10: persistent-B gemm (B-frags loop-invariant in registers).
// R11: prep kernel fuses deg_hist + x-fp16-convert + W-transpose (cvt work
//      hides under the random-atomic wall); scan_blocksums folded into
//      scan_apply; agg software-pipelined (pairs 3-ahead, h-rows 2-ahead).

#define D0 256
#define D1 128
#define D2 64
#define D3 32

#define FIX_SCALE 16777216.0f           // 2^24 fixed-point for degree
#define FIX_INV   (1.0f / 16777216.0f)

typedef _Float16 half8 __attribute__((ext_vector_type(8)));
typedef float floatx4 __attribute__((ext_vector_type(4)));

// ------------------------------------------- prep: deg_hist + conversions --
// Block ranges: [0,EB) edge histogram; [EB,EB+XB) x fp32->fp16; rest W^T cvt.
__global__ __launch_bounds__(256) void prep_kernel(
        const int* __restrict__ ei, const float* __restrict__ ew,
        unsigned long long* __restrict__ pk, int* __restrict__ rank, int E,
        const float* __restrict__ x, _Float16* __restrict__ x16, int xElems,
        const float* __restrict__ W1, _Float16* __restrict__ Wt1,
        const float* __restrict__ W2, _Float16* __restrict__ Wt2,
        const float* __restrict__ W3, _Float16* __restrict__ Wt3,
        int EB, int XB) {
    const int b = blockIdx.x;
    const int tid = threadIdx.x;
    if (b < EB) {
        // ---- degree + histogram (packed 64-bit atomic; old>>32 = rank) ----
        int e = b * 256 + tid;
        if (e < E) {
            int c = ei[E + e];
            unsigned int wfix = (unsigned int)(ew[e] * FIX_SCALE + 0.5f);
            unsigned long long old =
                atomicAdd(&pk[c], (1ULL << 32) | (unsigned long long)wfix);
            rank[e] = (int)(old >> 32);
        }
    } else if (b < EB + XB) {
        // ---- x fp32 -> fp16, 8 elems/thread ----
        int i = ((b - EB) * 256 + tid) * 8;
        if (i < xElems) {
            float4 f0 = *(const float4*)&x[i];
            float4 f1 = *(const float4*)&x[i + 4];
            half8 v;
            v[0] = (_Float16)f0.x; v[1] = (_Float16)f0.y;
            v[2] = (_Float16)f0.z; v[3] = (_Float16)f0.w;
            v[4] = (_Float16)f1.x; v[5] = (_Float16)f1.y;
            v[6] = (_Float16)f1.z; v[7] = (_Float16)f1.w;
            *(half8*)&x16[i] = v;
        }
    } else {
        // ---- W transpose + convert: Wt[n][k] = (fp16) W[k][n] ----
        int idx = (b - EB - XB) * 256 + tid;
        if (idx < D0 * D1) {
            int k = idx / D1, n = idx % D1;
            Wt1[n * D0 + k] = (_Float16)W1[idx];
        } else if (idx < D0 * D1 + D1 * D2) {
            int j = idx - D0 * D1;
            int k = j / D2, n = j % D2;
            Wt2[n * D1 + k] = (_Float16)W2[j];
        } else if (idx < D0 * D1 + D1 * D2 + D2 * D3) {
            int j = idx - D0 * D1 - D1 * D2;
            int k = j / D3, n = j % D3;
            Wt3[n * D2 + k] = (_Float16)W3[j];
        }
    }
}

// --------------------------------------------- 2-phase exclusive scan ------
// Phase 1 (fused): unpack pk -> dinv, cnt; per-block reduce cnt -> blockSum.
__global__ __launch_bounds__(256) void scan_reduce(const unsigned long long* __restrict__ pk,
                                                   float* __restrict__ dinv,
                                                   int* __restrict__ cnt,
                                                   int* __restrict__ blockSum, int N) {
    __shared__ int s[256];
    const int t = threadIdx.x;
    const int i = blockIdx.x * 256 + t;
    int v = 0;
    if (i < N) {
        unsigned long long p = pk[i];
        float d = (float)(unsigned int)(p & 0xffffffffULL) * FIX_INV + 1.0f;  // +1 self-loop
        dinv[i] = rsqrtf(d);
        v = (int)(p >> 32);
        cnt[i] = v;
    }
    s[t] = v;
    __syncthreads();
#pragma unroll
    for (int off = 128; off > 0; off >>= 1) {
        if (t < off) s[t] += s[t + off];
        __syncthreads();
    }
    if (t == 0) blockSum[blockIdx.x] = s[0];
}

// Phase 2: every block scans the (<=256) block sums in LDS, then scans its
// own 256-chunk of cnt -> row_ptr. Block 0 also writes row_ptr[N].
__global__ __launch_bounds__(256) void scan_apply(const int* __restrict__ cnt,
                                                  const int* __restrict__ blockSum,
                                                  int* __restrict__ row_ptr, int N, int B) {
    __shared__ int bs[256];
    __shared__ int s[256];
    const int t = threadIdx.x;
    // scan block sums (inclusive) in LDS
    bs[t] = (t < B) ? blockSum[t] : 0;
    __syncthreads();
#pragma unroll
    for (int off = 1; off < 256; off <<= 1) {
        int u = (t >= off) ? bs[t - off] : 0;
        __syncthreads();
        bs[t] += u;
        __syncthreads();
    }
    const int myOff = (blockIdx.x > 0) ? bs[blockIdx.x - 1] : 0;
    // scan own chunk
    const int i = blockIdx.x * 256 + t;
    const int v = (i < N) ? cnt[i] : 0;
    s[t] = v;
    __syncthreads();
#pragma unroll
    for (int off = 1; off < 256; off <<= 1) {
        int u = (t >= off) ? s[t - off] : 0;
        __syncthreads();
        s[t] += u;
        __syncthreads();
    }
    if (i < N) row_ptr[i] = s[t] - v + myOff;
    if (blockIdx.x == 0 && t == 0) row_ptr[N] = bs[B - 1];
}

// ------------------------------------------------- bucket fill (CSR) -------
__global__ void fill_kernel(const int* __restrict__ ei, const float* __restrict__ ew,
                            const float* __restrict__ dinv,
                            const int* __restrict__ row_ptr, const int* __restrict__ rank,
                            int2* __restrict__ pairs, int E) {
    int e = blockIdx.x * blockDim.x + threadIdx.x;
    if (e < E) {
        int r = ei[e];
        int c = ei[E + e];
        float w = dinv[r] * ew[e] * dinv[c];
        pairs[row_ptr[c] + rank[e]] = make_int2(r, __float_as_int(w));
    }
}

// ----------------------------------------------------------- MFMA GEMM -----
// H[N,BN] (fp16) = X[N,K] (fp16) @ Wt^T, Wt is [BN][K] fp16.
// Each wave owns a fixed 32-col group: B-frags loaded ONCE (loop-invariant),
// grid-stride over 16-row slabs with next-slab A prefetch. No LDS/barriers.
template <int K, int BN>
__global__ __launch_bounds__(256) void mfma_gemm(const _Float16* __restrict__ X,
                                                 const _Float16* __restrict__ Wt,
                                                 _Float16* __restrict__ H, int N) {
    constexpr int NC = K / 32;        // k-chunks
    constexpr int CG = BN / 32;       // col groups (waves per slab)
    const int w = blockIdx.x * 4 + (threadIdx.x >> 6);
    const int lane = threadIdx.x & 63;
    const int quad = lane >> 4;
    const int m = lane & 15;
    const int cg = w & (CG - 1);
    const int nslab = N >> 4;         // N multiple of 16
    const int stride = (gridDim.x * 4) / CG;
    int slab = w / CG;
    if (slab >= nslab) return;
    const int n0 = cg * 32;

    half8 b0[NC], b1[NC];
#pragma unroll
    for (int c = 0; c < NC; ++c) {
        b0[c] = *(const half8*)&Wt[(size_t)(n0 + m) * K + c * 32 + quad * 8];
        b1[c] = *(const half8*)&Wt[(size_t)(n0 + 16 + m) * K + c * 32 + quad * 8];
    }

    half8 a[NC];
#pragma unroll
    for (int c = 0; c < NC; ++c)
        a[c] = *(const half8*)&X[(size_t)(slab * 16 + m) * K + c * 32 + quad * 8];

    while (true) {
        const int next = slab + stride;
        half8 an[NC];
        if (next < nslab) {
#pragma unroll
            for (int c = 0; c < NC; ++c)
                an[c] = *(const half8*)&X[(size_t)(next * 16 + m) * K + c * 32 + quad * 8];
        }

        floatx4 acc0 = (floatx4){0.f, 0.f, 0.f, 0.f};
        floatx4 acc1 = (floatx4){0.f, 0.f, 0.f, 0.f};
#pragma unroll
        for (int c = 0; c < NC; ++c) {
            acc0 = __builtin_amdgcn_mfma_f32_16x16x32_f16(a[c], b0[c], acc0, 0, 0, 0);
            acc1 = __builtin_amdgcn_mfma_f32_16x16x32_f16(a[c], b1[c], acc1, 0, 0, 0);
        }

        const int r0 = slab * 16 + quad * 4;
#pragma unroll
        for (int r = 0; r < 4; ++r) {
            H[(size_t)(r0 + r) * BN + n0 + m]      = (_Float16)acc0[r];
            H[(size_t)(r0 + r) * BN + n0 + 16 + m] = (_Float16)acc1[r];
        }

        if (next >= nslab) break;
        slab = next;
#pragma unroll
        for (int c = 0; c < NC; ++c) a[c] = an[c];
    }
}

// -------------------------------------------- fused aggregate + epilogue ----
// Software-pipelined: pair loads 3 ahead, h-row loads 2 ahead (clamped).
template <int D, typename OUT>
__global__ __launch_bounds__(256) void agg_kernel(const _Float16* __restrict__ H,
                                                  const int* __restrict__ row_ptr,
                                                  const int2* __restrict__ pairs,
                                                  const float* __restrict__ dinv,
                                                  const float* __restrict__ bias,
                                                  OUT* __restrict__ out, int N) {
    constexpr int TPN = D / 8;        // threads per node (8 halves = 16B each)
    constexpr int NPB = 256 / TPN;    // nodes per block
    const int tid = threadIdx.x;
    const int g = tid / TPN;
    const int lane = tid % TPN;
    const int node = blockIdx.x * NPB + g;
    if (node >= N) return;

    const int beg = row_ptr[node];
    const int end = row_ptr[node + 1];
    float acc[8];
#pragma unroll
    for (int j = 0; j < 8; ++j) acc[j] = 0.0f;

    if (end > beg) {
        const int last = end - 1;
        int2 p0 = pairs[beg];
        int2 p1 = pairs[min(beg + 1, last)];
        int2 p2 = pairs[min(beg + 2, last)];
        half8 u0 = *(const half8*)&H[(size_t)p0.x * D + lane * 8];
        half8 u1 = *(const half8*)&H[(size_t)p1.x * D + lane * 8];
        for (int k = beg; k < end; ++k) {
            int2 p3 = pairs[min(k + 3, last)];
            half8 u2 = *(const half8*)&H[(size_t)p2.x * D + lane * 8];
            float w = __int_as_float(p0.y);
#pragma unroll
            for (int j = 0; j < 8; ++j) acc[j] = fmaf(w, (float)u0[j], acc[j]);
            p0 = p1; p1 = p2; p2 = p3;
            u0 = u1; u1 = u2;
        }
    }
    // self-loop + bias + relu
    float di = dinv[node];
    float d2 = di * di;
    {
        half8 u = *(const half8*)&H[(size_t)node * D + lane * 8];
#pragma unroll
        for (int j = 0; j < 8; ++j) acc[j] = fmaf(d2, (float)u[j], acc[j]);
    }
    float b[8];
    *(float4*)&b[0] = *(const float4*)&bias[lane * 8];
    *(float4*)&b[4] = *(const float4*)&bias[lane * 8 + 4];
#pragma unroll
    for (int j = 0; j < 8; ++j) acc[j] = fmaxf(acc[j] + b[j], 0.f);

    if constexpr (sizeof(OUT) == 2) {
        half8 o;
#pragma unroll
        for (int j = 0; j < 8; ++j) o[j] = (_Float16)acc[j];
        *(half8*)&out[(size_t)node * D + lane * 8] = o;
    } else {
        float* dst = (float*)&out[(size_t)node * D + lane * 8];
        *(float4*)&dst[0] = make_float4(acc[0], acc[1], acc[2], acc[3]);
        *(float4*)&dst[4] = make_float4(acc[4], acc[5], acc[6], acc[7]);
    }
}

// ---------------------------------------------------------------- launch ----
extern "C" void kernel_launch(void* const* d_in, const int* in_sizes, int n_in,
                              void* d_out, int out_size, void* d_ws, size_t ws_size,
                              hipStream_t stream) {
    const float* x   = (const float*)d_in[0];
    const int* ei    = (const int*)d_in[1];
    const float* ew  = (const float*)d_in[2];
    const float* W1  = (const float*)d_in[3];
    const float* b1  = (const float*)d_in[4];
    const float* W2  = (const float*)d_in[5];
    const float* b2  = (const float*)d_in[6];
    const float* W3  = (const float*)d_in[7];
    const float* b3  = (const float*)d_in[8];
    float* out = (float*)d_out;

    const int N = in_sizes[0] / D0;   // 50000
    const int E = in_sizes[2];        // 800000
    (void)n_in; (void)out_size; (void)ws_size;

    // ---- workspace carving ----
    char* ws = (char*)d_ws;
    size_t off = 0;
    auto carve = [&](size_t bytes) -> void* {
        void* p = (void*)(ws + off);
        off += (bytes + 255) & ~(size_t)255;
        return p;
    };
    unsigned long long* pk = (unsigned long long*)carve((size_t)N * 8);
    float* dinv    = (float*)carve((size_t)N * 4);
    int*   cnt     = (int*)carve((size_t)N * 4);
    int*   row_ptr = (int*)carve((size_t)(N + 1) * 4);
    int*   rank    = (int*)carve((size_t)E * 4);
    int*   bsum    = (int*)carve(256 * 4);
    int2*  pairs   = (int2*)carve((size_t)E * 8);
    _Float16* Wt1  = (_Float16*)carve((size_t)D0 * D1 * 2);
    _Float16* Wt2  = (_Float16*)carve((size_t)D1 * D2 * 2);
    _Float16* Wt3  = (_Float16*)carve((size_t)D2 * D3 * 2);
    _Float16* x16  = (_Float16*)carve((size_t)N * D0 * 2);  // 25.6 MB
    _Float16* bufH = (_Float16*)carve((size_t)N * D1 * 2);  // h1/h2/h3
    _Float16* bufO = (_Float16*)carve((size_t)N * D1 * 2);  // out1/out2 (fp16)

    _Float16* h1   = bufH;               // N x 128 fp16
    _Float16* out1 = bufO;               // N x 128 fp16 ; x for layer 2
    _Float16* h2   = bufH;               // N x 64 fp16 (h1 dead)
    _Float16* out2 = bufO;               // N x 64 fp16 (out1 dead after gemm2)
    _Float16* h3   = bufH;               // N x 32 fp16 (h2 dead)

    const int eb = (E + 255) / 256;       // 3125
    const int xElems = N * D0;
    const int xb = (xElems / 8 + 255) / 256;  // 6250
    const int wElems = D0 * D1 + D1 * D2 + D2 * D3;  // 43008
    const int wb = (wElems + 255) / 256;  // 168
    const int scanB = (N + 255) / 256;    // 196 (must be <= 256)
    const int gB = 768;                   // gemm blocks (3/CU, 3072 waves)

    // ---- prep: histogram + conversions (one kernel) ----
    hipMemsetAsync(pk, 0, (size_t)N * 8, stream);
    prep_kernel<<<eb + xb + wb, 256, 0, stream>>>(
        ei, ew, pk, rank, E, x, x16, xElems,
        W1, Wt1, W2, Wt2, W3, Wt3, eb, xb);

    // ---- CSR build ----
    scan_reduce<<<scanB, 256, 0, stream>>>(pk, dinv, cnt, bsum, N);
    scan_apply<<<scanB, 256, 0, stream>>>(cnt, bsum, row_ptr, N, scanB);
    fill_kernel<<<eb, 256, 0, stream>>>(ei, ew, dinv, row_ptr, rank, pairs, E);

    // ---- layer 1: 256 -> 128 ----
    mfma_gemm<D0, D1><<<gB, 256, 0, stream>>>(x16, Wt1, h1, N);
    agg_kernel<D1, _Float16><<<(N + 15) / 16, 256, 0, stream>>>(h1, row_ptr, pairs, dinv, b1, out1, N);

    // ---- layer 2: 128 -> 64 ----
    mfma_gemm<D1, D2><<<gB, 256, 0, stream>>>(out1, Wt2, h2, N);
    agg_kernel<D2, _Float16><<<(N + 31) / 32, 256, 0, stream>>>(h2, row_ptr, pairs, dinv, b2, out2, N);

    // ---- layer 3: 64 -> 32 ----
    mfma_gemm<D2, D3><<<gB, 256, 0, stream>>>(out2, Wt3, h3, N);
    agg_kernel<D3, float><<<(N + 63) / 64, 256, 0, stream>>>(h3, row_ptr, pairs, dinv, b3, out, N);
}

// Round 13
// 260.916 us; speedup vs baseline: 1.1803x; 1.0310x over previous
//
#include <hip/hip_runtime.h>
#include <hip/hip_fp16.h>

// GCN encoder: 3x (GCNConv + ReLU), dims 256->128->64->32
// N=50000 nodes, E=800000 edges. edge_index delivered as int32 (harness).
// R2: CSR gather.  R3/R11: multi-block scan, fused.  R4: packed deg+cnt atomic.
// R5: fp16 H buffers.  R6: MFMA gemms.  R7: atomic-free fill via rank.
// R10: persistent-B gemm (B-frags loop-invariant in registers).
// R11: agg software-pipelined; conversions hidden under atomic wall.
// R12: gemm1 fused INTO the histogram kernel (no data dependency; MFMA work
//      co-schedules on CUs the atomic wall leaves idle). All gemms read
//      fp32 X/W with in-register fp16 conversion -> xcvt/wcvt buffers gone.

#define D0 256
#define D1 128
#define D2 64
#define D3 32

#define FIX_SCALE 16777216.0f           // 2^24 fixed-point for degree
#define FIX_INV   (1.0f / 16777216.0f)

typedef _Float16 half8 __attribute__((ext_vector_type(8)));
typedef float floatx4 __attribute__((ext_vector_type(4)));

// ------------------------------------------------------ gemm device core ---
// H[N,BN] (fp16) = X[N,K] @ W[K,BN] (both possibly fp32, cvt in-register).
// Wave w owns col group (w % CG)*32 (2 MFMA tiles): B-frags loaded once
// (loop-invariant), grid-stride over 16-row slabs with next-slab A prefetch.
// A[m=lane&15][k=quad*8+j]; B[k][n]; D row=quad*4+reg.
template <typename SRC>
__device__ __forceinline__ half8 loadA(const SRC* __restrict__ p) {
    if constexpr (sizeof(SRC) == 4) {
        float4 f0 = *(const float4*)p;
        float4 f1 = *(const float4*)(p + 4);
        half8 v;
        v[0] = (_Float16)f0.x; v[1] = (_Float16)f0.y;
        v[2] = (_Float16)f0.z; v[3] = (_Float16)f0.w;
        v[4] = (_Float16)f1.x; v[5] = (_Float16)f1.y;
        v[6] = (_Float16)f1.z; v[7] = (_Float16)f1.w;
        return v;
    } else {
        return *(const half8*)p;
    }
}

template <int K, int BN, typename SRC>
__device__ __forceinline__ void gemm_work(const SRC* __restrict__ X,
                                          const float* __restrict__ W,
                                          _Float16* __restrict__ H, int N,
                                          int w, int totalWaves) {
    constexpr int NC = K / 32;        // k-chunks
    constexpr int CG = BN / 32;       // col groups (waves per slab)
    const int lane = threadIdx.x & 63;
    const int quad = lane >> 4;
    const int m = lane & 15;
    const int cg = w & (CG - 1);
    const int nslab = N >> 4;         // N multiple of 16
    const int stride = totalWaves / CG;
    int slab = w / CG;
    if (slab >= nslab) return;
    const int n0 = cg * 32;

    // ---- persistent B-frags: W fp32, strided, loaded once per wave ----
    half8 b0[NC], b1[NC];
#pragma unroll
    for (int c = 0; c < NC; ++c) {
#pragma unroll
        for (int j = 0; j < 8; ++j) {
            int k = c * 32 + quad * 8 + j;
            b0[c][j] = (_Float16)W[(size_t)k * BN + n0 + m];
            b1[c][j] = (_Float16)W[(size_t)k * BN + n0 + 16 + m];
        }
    }

    half8 a[NC];
#pragma unroll
    for (int c = 0; c < NC; ++c)
        a[c] = loadA(&X[(size_t)(slab * 16 + m) * K + c * 32 + quad * 8]);

    while (true) {
        const int next = slab + stride;
        half8 an[NC];
        if (next < nslab) {
#pragma unroll
            for (int c = 0; c < NC; ++c)
                an[c] = loadA(&X[(size_t)(next * 16 + m) * K + c * 32 + quad * 8]);
        }

        floatx4 acc0 = (floatx4){0.f, 0.f, 0.f, 0.f};
        floatx4 acc1 = (floatx4){0.f, 0.f, 0.f, 0.f};
#pragma unroll
        for (int c = 0; c < NC; ++c) {
            acc0 = __builtin_amdgcn_mfma_f32_16x16x32_f16(a[c], b0[c], acc0, 0, 0, 0);
            acc1 = __builtin_amdgcn_mfma_f32_16x16x32_f16(a[c], b1[c], acc1, 0, 0, 0);
        }

        const int r0 = slab * 16 + quad * 4;
#pragma unroll
        for (int r = 0; r < 4; ++r) {
            H[(size_t)(r0 + r) * BN + n0 + m]      = (_Float16)acc0[r];
            H[(size_t)(r0 + r) * BN + n0 + 16 + m] = (_Float16)acc1[r];
        }

        if (next >= nslab) break;
        slab = next;
#pragma unroll
        for (int c = 0; c < NC; ++c) a[c] = an[c];
    }
}

// ------------------------------- fused histogram + gemm1 (independent) -----
// Blocks [0,gB): gemm1 (x fp32 @ W1 fp32 -> h1 fp16).
// Blocks [gB,..): packed deg+cnt atomic histogram; old>>32 = edge rank.
__global__ __launch_bounds__(256) void hist_gemm1_kernel(
        const float* __restrict__ x, const float* __restrict__ W1,
        _Float16* __restrict__ h1, int N,
        const int* __restrict__ ei, const float* __restrict__ ew,
        unsigned long long* __restrict__ pk, int* __restrict__ rank, int E,
        int gB) {
    const int b = blockIdx.x;
    if (b < gB) {
        gemm_work<D0, D1, float>(x, W1, h1, N, b * 4 + (threadIdx.x >> 6), gB * 4);
    } else {
        int e = (b - gB) * 256 + threadIdx.x;
        if (e < E) {
            int c = ei[E + e];
            unsigned int wfix = (unsigned int)(ew[e] * FIX_SCALE + 0.5f);
            unsigned long long old =
                atomicAdd(&pk[c], (1ULL << 32) | (unsigned long long)wfix);
            rank[e] = (int)(old >> 32);
        }
    }
}

// ------------------------------------------------------ standalone gemms ---
template <int K, int BN, typename SRC>
__global__ __launch_bounds__(256) void mfma_gemm(const SRC* __restrict__ X,
                                                 const float* __restrict__ W,
                                                 _Float16* __restrict__ H, int N) {
    gemm_work<K, BN, SRC>(X, W, H, N, blockIdx.x * 4 + (threadIdx.x >> 6), gridDim.x * 4);
}

// --------------------------------------------- 2-phase exclusive scan ------
__global__ __launch_bounds__(256) void scan_reduce(const unsigned long long* __restrict__ pk,
                                                   float* __restrict__ dinv,
                                                   int* __restrict__ cnt,
                                                   int* __restrict__ blockSum, int N) {
    __shared__ int s[256];
    const int t = threadIdx.x;
    const int i = blockIdx.x * 256 + t;
    int v = 0;
    if (i < N) {
        unsigned long long p = pk[i];
        float d = (float)(unsigned int)(p & 0xffffffffULL) * FIX_INV + 1.0f;  // +1 self-loop
        dinv[i] = rsqrtf(d);
        v = (int)(p >> 32);
        cnt[i] = v;
    }
    s[t] = v;
    __syncthreads();
#pragma unroll
    for (int off = 128; off > 0; off >>= 1) {
        if (t < off) s[t] += s[t + off];
        __syncthreads();
    }
    if (t == 0) blockSum[blockIdx.x] = s[0];
}

__global__ __launch_bounds__(256) void scan_apply(const int* __restrict__ cnt,
                                                  const int* __restrict__ blockSum,
                                                  int* __restrict__ row_ptr, int N, int B) {
    __shared__ int bs[256];
    __shared__ int s[256];
    const int t = threadIdx.x;
    bs[t] = (t < B) ? blockSum[t] : 0;
    __syncthreads();
#pragma unroll
    for (int off = 1; off < 256; off <<= 1) {
        int u = (t >= off) ? bs[t - off] : 0;
        __syncthreads();
        bs[t] += u;
        __syncthreads();
    }
    const int myOff = (blockIdx.x > 0) ? bs[blockIdx.x - 1] : 0;
    const int i = blockIdx.x * 256 + t;
    const int v = (i < N) ? cnt[i] : 0;
    s[t] = v;
    __syncthreads();
#pragma unroll
    for (int off = 1; off < 256; off <<= 1) {
        int u = (t >= off) ? s[t - off] : 0;
        __syncthreads();
        s[t] += u;
        __syncthreads();
    }
    if (i < N) row_ptr[i] = s[t] - v + myOff;
    if (blockIdx.x == 0 && t == 0) row_ptr[N] = bs[B - 1];
}

// ------------------------------------------------- bucket fill (CSR) -------
__global__ void fill_kernel(const int* __restrict__ ei, const float* __restrict__ ew,
                            const float* __restrict__ dinv,
                            const int* __restrict__ row_ptr, const int* __restrict__ rank,
                            int2* __restrict__ pairs, int E) {
    int e = blockIdx.x * blockDim.x + threadIdx.x;
    if (e < E) {
        int r = ei[e];
        int c = ei[E + e];
        float w = dinv[r] * ew[e] * dinv[c];
        pairs[row_ptr[c] + rank[e]] = make_int2(r, __float_as_int(w));
    }
}

// -------------------------------------------- fused aggregate + epilogue ----
// Software-pipelined: pair loads 3 ahead, h-row loads 2 ahead (clamped).
template <int D, typename OUT>
__global__ __launch_bounds__(256) void agg_kernel(const _Float16* __restrict__ H,
                                                  const int* __restrict__ row_ptr,
                                                  const int2* __restrict__ pairs,
                                                  const float* __restrict__ dinv,
                                                  const float* __restrict__ bias,
                                                  OUT* __restrict__ out, int N) {
    constexpr int TPN = D / 8;        // threads per node (8 halves = 16B each)
    constexpr int NPB = 256 / TPN;    // nodes per block
    const int tid = threadIdx.x;
    const int g = tid / TPN;
    const int lane = tid % TPN;
    const int node = blockIdx.x * NPB + g;
    if (node >= N) return;

    const int beg = row_ptr[node];
    const int end = row_ptr[node + 1];
    float acc[8];
#pragma unroll
    for (int j = 0; j < 8; ++j) acc[j] = 0.0f;

    if (end > beg) {
        const int last = end - 1;
        int2 p0 = pairs[beg];
        int2 p1 = pairs[min(beg + 1, last)];
        int2 p2 = pairs[min(beg + 2, last)];
        half8 u0 = *(const half8*)&H[(size_t)p0.x * D + lane * 8];
        half8 u1 = *(const half8*)&H[(size_t)p1.x * D + lane * 8];
        for (int k = beg; k < end; ++k) {
            int2 p3 = pairs[min(k + 3, last)];
            half8 u2 = *(const half8*)&H[(size_t)p2.x * D + lane * 8];
            float w = __int_as_float(p0.y);
#pragma unroll
            for (int j = 0; j < 8; ++j) acc[j] = fmaf(w, (float)u0[j], acc[j]);
            p0 = p1; p1 = p2; p2 = p3;
            u0 = u1; u1 = u2;
        }
    }
    // self-loop + bias + relu
    float di = dinv[node];
    float d2 = di * di;
    {
        half8 u = *(const half8*)&H[(size_t)node * D + lane * 8];
#pragma unroll
        for (int j = 0; j < 8; ++j) acc[j] = fmaf(d2, (float)u[j], acc[j]);
    }
    float b[8];
    *(float4*)&b[0] = *(const float4*)&bias[lane * 8];
    *(float4*)&b[4] = *(const float4*)&bias[lane * 8 + 4];
#pragma unroll
    for (int j = 0; j < 8; ++j) acc[j] = fmaxf(acc[j] + b[j], 0.f);

    if constexpr (sizeof(OUT) == 2) {
        half8 o;
#pragma unroll
        for (int j = 0; j < 8; ++j) o[j] = (_Float16)acc[j];
        *(half8*)&out[(size_t)node * D + lane * 8] = o;
    } else {
        float* dst = (float*)&out[(size_t)node * D + lane * 8];
        *(float4*)&dst[0] = make_float4(acc[0], acc[1], acc[2], acc[3]);
        *(float4*)&dst[4] = make_float4(acc[4], acc[5], acc[6], acc[7]);
    }
}

// ---------------------------------------------------------------- launch ----
extern "C" void kernel_launch(void* const* d_in, const int* in_sizes, int n_in,
                              void* d_out, int out_size, void* d_ws, size_t ws_size,
                              hipStream_t stream) {
    const float* x   = (const float*)d_in[0];
    const int* ei    = (const int*)d_in[1];
    const float* ew  = (const float*)d_in[2];
    const float* W1  = (const float*)d_in[3];
    const float* b1  = (const float*)d_in[4];
    const float* W2  = (const float*)d_in[5];
    const float* b2  = (const float*)d_in[6];
    const float* W3  = (const float*)d_in[7];
    const float* b3  = (const float*)d_in[8];
    float* out = (float*)d_out;

    const int N = in_sizes[0] / D0;   // 50000
    const int E = in_sizes[2];        // 800000
    (void)n_in; (void)out_size; (void)ws_size;

    // ---- workspace carving ----
    char* ws = (char*)d_ws;
    size_t off = 0;
    auto carve = [&](size_t bytes) -> void* {
        void* p = (void*)(ws + off);
        off += (bytes + 255) & ~(size_t)255;
        return p;
    };
    unsigned long long* pk = (unsigned long long*)carve((size_t)N * 8);
    float* dinv    = (float*)carve((size_t)N * 4);
    int*   cnt     = (int*)carve((size_t)N * 4);
    int*   row_ptr = (int*)carve((size_t)(N + 1) * 4);
    int*   rank    = (int*)carve((size_t)E * 4);
    int*   bsum    = (int*)carve(256 * 4);
    int2*  pairs   = (int2*)carve((size_t)E * 8);
    _Float16* bufH = (_Float16*)carve((size_t)N * D1 * 2);  // h1/h2/h3
    _Float16* bufO = (_Float16*)carve((size_t)N * D1 * 2);  // out1/out2 (fp16)

    _Float16* h1   = bufH;               // N x 128 fp16
    _Float16* out1 = bufO;               // N x 128 fp16 ; x for layer 2
    _Float16* h2   = bufH;               // N x 64 fp16 (h1 dead)
    _Float16* out2 = bufO;               // N x 64 fp16 (out1 dead after gemm2)
    _Float16* h3   = bufH;               // N x 32 fp16 (h2 dead)

    const int eb = (E + 255) / 256;       // 3125
    const int scanB = (N + 255) / 256;    // 196 (must be <= 256)
    const int gB = 768;                   // gemm blocks (3/CU, 3072 waves)

    // ---- fused: gemm1 + histogram (independent work, one dispatch) ----
    hipMemsetAsync(pk, 0, (size_t)N * 8, stream);
    hist_gemm1_kernel<<<gB + eb, 256, 0, stream>>>(
        x, W1, h1, N, ei, ew, pk, rank, E, gB);

    // ---- CSR build ----
    scan_reduce<<<scanB, 256, 0, stream>>>(pk, dinv, cnt, bsum, N);
    scan_apply<<<scanB, 256, 0, stream>>>(cnt, bsum, row_ptr, N, scanB);
    fill_kernel<<<eb, 256, 0, stream>>>(ei, ew, dinv, row_ptr, rank, pairs, E);

    // ---- layer 1 aggregate ----
    agg_kernel<D1, _Float16><<<(N + 15) / 16, 256, 0, stream>>>(h1, row_ptr, pairs, dinv, b1, out1, N);

    // ---- layer 2: 128 -> 64 ----
    mfma_gemm<D1, D2, _Float16><<<gB, 256, 0, stream>>>(out1, W2, h2, N);
    agg_kernel<D2, _Float16><<<(N + 31) / 32, 256, 0, stream>>>(h2, row_ptr, pairs, dinv, b2, out2, N);

    // ---- layer 3: 64 -> 32 ----
    mfma_gemm<D2, D3, _Float16><<<gB, 256, 0, stream>>>(out2, W3, h3, N);
    agg_kernel<D3, float><<<(N + 63) / 64, 256, 0, stream>>>(h3, row_ptr, pairs, dinv, b3, out, N);
}